// Round 1
// baseline (922.201 us; speedup 1.0000x reference)
//
#include <hip/hip_runtime.h>
#include <hip/hip_bf16.h>

// GCN 2-layer forward, two graphs, shared weights.
// Pipeline per graph: CSR build (hist/scan/scatter) -> H1=X@W1 -> Z=selu(spmm(H1)+b1)
//                     -> H2=Z@W2 -> out=l2norm(spmm(H2)+b2)
// All fp32. One wave (64 lanes) per row in spmm: lane == feature dim (HID=64).

__device__ __forceinline__ float selu_f(float x) {
    const float scale = 1.0507009873554805f;
    const float alpha = 1.6732632423543772f;
    return x > 0.0f ? scale * x : scale * alpha * (__expf(x) - 1.0f);
}

// ---------------- CSR build ----------------
__global__ void hist_kernel(const int* __restrict__ rows, int* __restrict__ counts, int E) {
    int e = blockIdx.x * blockDim.x + threadIdx.x;
    if (e < E) atomicAdd(&counts[rows[e]], 1);
}

// block of 256 threads scans 1024 counts -> local exclusive offsets + block total
__global__ void scan_a(const int* __restrict__ counts, int* __restrict__ offs,
                       int* __restrict__ partials, int N) {
    __shared__ int sh[256];
    int tid = threadIdx.x;
    int base = blockIdx.x * 1024 + tid * 4;
    int4 c = make_int4(0, 0, 0, 0);
    if (base + 3 < N) {
        c = *(const int4*)(counts + base);
    } else {
        if (base + 0 < N) c.x = counts[base + 0];
        if (base + 1 < N) c.y = counts[base + 1];
        if (base + 2 < N) c.z = counts[base + 2];
        if (base + 3 < N) c.w = counts[base + 3];
    }
    int tsum = c.x + c.y + c.z + c.w;
    sh[tid] = tsum;
    __syncthreads();
    int val = tsum;  // inclusive scan of per-thread sums (Hillis-Steele)
    for (int d = 1; d < 256; d <<= 1) {
        int t = (tid >= d) ? sh[tid - d] : 0;
        __syncthreads();
        val += t;
        sh[tid] = val;
        __syncthreads();
    }
    int excl = val - tsum;
    int4 o;
    o.x = excl;
    o.y = o.x + c.x;
    o.z = o.y + c.y;
    o.w = o.z + c.z;
    if (base + 3 < N) {
        *(int4*)(offs + base) = o;
    } else {
        if (base + 0 < N) offs[base + 0] = o.x;
        if (base + 1 < N) offs[base + 1] = o.y;
        if (base + 2 < N) offs[base + 2] = o.z;
        if (base + 3 < N) offs[base + 3] = o.w;
    }
    if (tid == 255) partials[blockIdx.x] = val;
}

// single block: exclusive scan of block partials (nb <= 128)
__global__ void scan_b(int* __restrict__ partials, int nb) {
    __shared__ int sh[128];
    int tid = threadIdx.x;
    int v = (tid < nb) ? partials[tid] : 0;
    sh[tid] = v;
    __syncthreads();
    int val = v;
    for (int d = 1; d < 128; d <<= 1) {
        int t = (tid >= d) ? sh[tid - d] : 0;
        __syncthreads();
        val += t;
        sh[tid] = val;
        __syncthreads();
    }
    if (tid < nb) partials[tid] = val - v;  // exclusive
}

// add block bases; also copy offs -> cursor for the scatter pass; set offs[N]=E
__global__ void scan_c(int* __restrict__ offs, int* __restrict__ cursor,
                       const int* __restrict__ partials, int N, int E) {
    int tid = threadIdx.x;
    int base = blockIdx.x * 1024 + tid * 4;
    int add = partials[blockIdx.x];
    if (base + 3 < N) {
        int4 o = *(int4*)(offs + base);
        o.x += add; o.y += add; o.z += add; o.w += add;
        *(int4*)(offs + base) = o;
        *(int4*)(cursor + base) = o;
    } else {
        for (int t = 0; t < 4; t++) {
            if (base + t < N) {
                int o = offs[base + t] + add;
                offs[base + t] = o;
                cursor[base + t] = o;
            }
        }
    }
    if (blockIdx.x == 0 && tid == 0) offs[N] = E;
}

__global__ void scatter_kernel(const int* __restrict__ rows, const int* __restrict__ cols,
                               const float* __restrict__ vals, int* __restrict__ cursor,
                               int* __restrict__ ecol, float* __restrict__ eval_, int E) {
    int e = blockIdx.x * blockDim.x + threadIdx.x;
    if (e < E) {
        int r = rows[e];
        int p = atomicAdd(&cursor[r], 1);
        ecol[p] = cols[e];
        eval_[p] = vals[e];
    }
}

// ---------------- dense GEMM: C[M,64] = A[M,K] @ W[K,64], fp32 ----------------
// 64x64 output tile per 256-thread block; K-chunks of 64 staged in LDS.
// Each thread: 4 rows x 4 cols, float4 LDS reads (stride 68 pad -> <=2-way bank alias, free).
__global__ __launch_bounds__(256) void gemm_n64(const float* __restrict__ A,
                                                const float* __restrict__ W,
                                                float* __restrict__ C, int M, int K) {
    __shared__ __align__(16) float Xs[64][68];
    __shared__ __align__(16) float Ws[64][68];
    int tid = threadIdx.x;
    int row0 = blockIdx.x * 64;
    int r0 = (tid >> 4) * 4;   // 0..60
    int c0 = (tid & 15) * 4;   // 0..60
    float acc[4][4] = {};
    for (int kc = 0; kc < K; kc += 64) {
#pragma unroll
        for (int v = 0; v < 4; v++) {
            int idx = v * 256 + tid;   // 1024 float4 units per tile
            int i = idx >> 4;          // tile row (X) / tile k (W)
            int j = (idx & 15) * 4;    // tile col
            int gr = row0 + i;
            float4 g = make_float4(0.f, 0.f, 0.f, 0.f);
            if (gr < M) g = *(const float4*)(A + (size_t)gr * K + kc + j);
            *(float4*)(&Xs[i][j]) = g;
            float4 wv = *(const float4*)(W + (size_t)(kc + i) * 64 + j);
            *(float4*)(&Ws[i][j]) = wv;
        }
        __syncthreads();
#pragma unroll
        for (int j = 0; j < 64; j += 4) {
            float4 a[4], b[4];
            a[0] = *(float4*)(&Xs[r0 + 0][j]);
            a[1] = *(float4*)(&Xs[r0 + 1][j]);
            a[2] = *(float4*)(&Xs[r0 + 2][j]);
            a[3] = *(float4*)(&Xs[r0 + 3][j]);
            b[0] = *(float4*)(&Ws[j + 0][c0]);
            b[1] = *(float4*)(&Ws[j + 1][c0]);
            b[2] = *(float4*)(&Ws[j + 2][c0]);
            b[3] = *(float4*)(&Ws[j + 3][c0]);
#pragma unroll
            for (int r = 0; r < 4; r++) {
                float ar[4] = {a[r].x, a[r].y, a[r].z, a[r].w};
#pragma unroll
                for (int t = 0; t < 4; t++) {
                    float bc[4] = {b[t].x, b[t].y, b[t].z, b[t].w};
#pragma unroll
                    for (int cc = 0; cc < 4; cc++)
                        acc[r][cc] = fmaf(ar[t], bc[cc], acc[r][cc]);
                }
            }
        }
        __syncthreads();
    }
#pragma unroll
    for (int r = 0; r < 4; r++) {
        int gr = row0 + r0 + r;
        if (gr < M) {
            float4 o = make_float4(acc[r][0], acc[r][1], acc[r][2], acc[r][3]);
            *(float4*)(C + (size_t)gr * 64 + c0) = o;
        }
    }
}

// ---------------- SpMM (CSR), one wave per row, lane = feature ----------------
__global__ __launch_bounds__(256) void spmm_selu(const int* __restrict__ offs,
                                                 const int* __restrict__ ecol,
                                                 const float* __restrict__ eval_,
                                                 const float* __restrict__ H,
                                                 const float* __restrict__ bias,
                                                 float* __restrict__ out, int N) {
    int row = blockIdx.x * 4 + (threadIdx.x >> 6);
    if (row >= N) return;
    int lane = threadIdx.x & 63;
    int s = offs[row], e = offs[row + 1];
    float acc0 = 0.f, acc1 = 0.f;
    int i = s;
    for (; i + 1 < e; i += 2) {
        int c0 = ecol[i], c1 = ecol[i + 1];
        float v0 = eval_[i], v1 = eval_[i + 1];
        acc0 = fmaf(v0, H[(size_t)c0 * 64 + lane], acc0);
        acc1 = fmaf(v1, H[(size_t)c1 * 64 + lane], acc1);
    }
    if (i < e) acc0 = fmaf(eval_[i], H[(size_t)ecol[i] * 64 + lane], acc0);
    float z = acc0 + acc1 + bias[lane];
    out[(size_t)row * 64 + lane] = selu_f(z);
}

__global__ __launch_bounds__(256) void spmm_norm(const int* __restrict__ offs,
                                                 const int* __restrict__ ecol,
                                                 const float* __restrict__ eval_,
                                                 const float* __restrict__ H,
                                                 const float* __restrict__ bias,
                                                 float* __restrict__ out, int N) {
    int row = blockIdx.x * 4 + (threadIdx.x >> 6);
    if (row >= N) return;
    int lane = threadIdx.x & 63;
    int s = offs[row], e = offs[row + 1];
    float acc0 = 0.f, acc1 = 0.f;
    int i = s;
    for (; i + 1 < e; i += 2) {
        int c0 = ecol[i], c1 = ecol[i + 1];
        float v0 = eval_[i], v1 = eval_[i + 1];
        acc0 = fmaf(v0, H[(size_t)c0 * 64 + lane], acc0);
        acc1 = fmaf(v1, H[(size_t)c1 * 64 + lane], acc1);
    }
    if (i < e) acc0 = fmaf(eval_[i], H[(size_t)ecol[i] * 64 + lane], acc0);
    float z = acc0 + acc1 + bias[lane];
    float s2 = z * z;
#pragma unroll
    for (int d = 32; d > 0; d >>= 1) s2 += __shfl_xor(s2, d, 64);
    float inv = 1.0f / fmaxf(sqrtf(s2), 1e-12f);
    out[(size_t)row * 64 + lane] = z * inv;
}

extern "C" void kernel_launch(void* const* d_in, const int* in_sizes, int n_in,
                              void* d_out, int out_size, void* d_ws, size_t ws_size,
                              hipStream_t stream) {
    const int IN_DIM = 256, HID = 64;
    const int N = in_sizes[0] / IN_DIM;   // 100000
    const int E = in_sizes[2];            // 1200000

    const float* X[2]    = {(const float*)d_in[0], (const float*)d_in[1]};
    const int*   rows[2] = {(const int*)d_in[2], (const int*)d_in[5]};
    const int*   cols[2] = {(const int*)d_in[3], (const int*)d_in[6]};
    const float* vals[2] = {(const float*)d_in[4], (const float*)d_in[7]};
    const float* W1 = (const float*)d_in[8];
    const float* b1 = (const float*)d_in[9];
    const float* W2 = (const float*)d_in[10];
    const float* b2 = (const float*)d_in[11];
    float* out = (float*)d_out;

    // workspace carve (~62 MB)
    char* w = (char*)d_ws;
    float* bufA   = (float*)w; w += (size_t)N * HID * sizeof(float);
    float* bufB   = (float*)w; w += (size_t)N * HID * sizeof(float);
    int*   counts = (int*)w;   w += (size_t)N * sizeof(int);
    int*   offs   = (int*)w;   w += (size_t)(N + 1) * sizeof(int);
    int*   cursor = (int*)w;   w += (size_t)N * sizeof(int);
    int*   partials = (int*)w; w += 1024;
    int*   ecol   = (int*)w;   w += (size_t)E * sizeof(int);
    float* eval_  = (float*)w; w += (size_t)E * sizeof(float);

    const int nbScan = (N + 1023) / 1024;          // 98 (<=128 for scan_b)
    const int nbEdge = (E + 255) / 256;            // 4688
    const int nbGemm = (N + 63) / 64;              // 1563
    const int nbRow  = (N + 3) / 4;                // 25000

    for (int g = 0; g < 2; g++) {
        // CSR build
        hipMemsetAsync(counts, 0, (size_t)N * sizeof(int), stream);
        hist_kernel<<<nbEdge, 256, 0, stream>>>(rows[g], counts, E);
        scan_a<<<nbScan, 256, 0, stream>>>(counts, offs, partials, N);
        scan_b<<<1, 128, 0, stream>>>(partials, nbScan);
        scan_c<<<nbScan, 256, 0, stream>>>(offs, cursor, partials, N, E);
        scatter_kernel<<<nbEdge, 256, 0, stream>>>(rows[g], cols[g], vals[g], cursor,
                                                   ecol, eval_, E);
        // layer 1
        gemm_n64<<<nbGemm, 256, 0, stream>>>(X[g], W1, bufA, N, IN_DIM);
        spmm_selu<<<nbRow, 256, 0, stream>>>(offs, ecol, eval_, bufA, b1, bufB, N);
        // layer 2
        gemm_n64<<<nbGemm, 256, 0, stream>>>(bufB, W2, bufA, N, HID);
        spmm_norm<<<nbRow, 256, 0, stream>>>(offs, ecol, eval_, bufA, b2,
                                             out + (size_t)g * N * HID, N);
    }
}

// Round 2
// 817.671 us; speedup vs baseline: 1.1278x; 1.1278x over previous
//
#include <hip/hip_runtime.h>
#include <hip/hip_bf16.h>

// GCN 2-layer forward, two graphs, shared weights.
// Pipeline per graph: CSR build (hist/scan/scatter int2) -> H1=X@W1
//   -> Z=selu(spmm(H1)+b1) -> H2=Z@W2 -> out=l2norm(spmm(H2)+b2)
// All fp32. One wave (64 lanes) per row in spmm: lane == feature dim (HID=64).
// Edge payload (col,val) packed as int2: one 8B random store in scatter
// (halves write-allocate line thrash vs two 4B stores), one scalar 8B load
// per edge in spmm (addresses are wave-uniform after readfirstlane).

__device__ __forceinline__ float selu_f(float x) {
    const float scale = 1.0507009873554805f;
    const float alpha = 1.6732632423543772f;
    return x > 0.0f ? scale * x : scale * alpha * (__expf(x) - 1.0f);
}

// ---------------- CSR build ----------------
__global__ void hist_kernel(const int* __restrict__ rows, int* __restrict__ counts, int E) {
    int e = blockIdx.x * blockDim.x + threadIdx.x;
    if (e < E) atomicAdd(&counts[rows[e]], 1);
}

// block of 256 threads scans 1024 counts -> local exclusive offsets + block total
__global__ void scan_a(const int* __restrict__ counts, int* __restrict__ offs,
                       int* __restrict__ partials, int N) {
    __shared__ int sh[256];
    int tid = threadIdx.x;
    int base = blockIdx.x * 1024 + tid * 4;
    int4 c = make_int4(0, 0, 0, 0);
    if (base + 3 < N) {
        c = *(const int4*)(counts + base);
    } else {
        if (base + 0 < N) c.x = counts[base + 0];
        if (base + 1 < N) c.y = counts[base + 1];
        if (base + 2 < N) c.z = counts[base + 2];
        if (base + 3 < N) c.w = counts[base + 3];
    }
    int tsum = c.x + c.y + c.z + c.w;
    sh[tid] = tsum;
    __syncthreads();
    int val = tsum;  // inclusive scan of per-thread sums (Hillis-Steele)
    for (int d = 1; d < 256; d <<= 1) {
        int t = (tid >= d) ? sh[tid - d] : 0;
        __syncthreads();
        val += t;
        sh[tid] = val;
        __syncthreads();
    }
    int excl = val - tsum;
    int4 o;
    o.x = excl;
    o.y = o.x + c.x;
    o.z = o.y + c.y;
    o.w = o.z + c.z;
    if (base + 3 < N) {
        *(int4*)(offs + base) = o;
    } else {
        if (base + 0 < N) offs[base + 0] = o.x;
        if (base + 1 < N) offs[base + 1] = o.y;
        if (base + 2 < N) offs[base + 2] = o.z;
        if (base + 3 < N) offs[base + 3] = o.w;
    }
    if (tid == 255) partials[blockIdx.x] = val;
}

// single block: exclusive scan of block partials (nb <= 128)
__global__ void scan_b(int* __restrict__ partials, int nb) {
    __shared__ int sh[128];
    int tid = threadIdx.x;
    int v = (tid < nb) ? partials[tid] : 0;
    sh[tid] = v;
    __syncthreads();
    int val = v;
    for (int d = 1; d < 128; d <<= 1) {
        int t = (tid >= d) ? sh[tid - d] : 0;
        __syncthreads();
        val += t;
        sh[tid] = val;
        __syncthreads();
    }
    if (tid < nb) partials[tid] = val - v;  // exclusive
}

// add block bases; also copy offs -> cursor for the scatter pass; set offs[N]=E
__global__ void scan_c(int* __restrict__ offs, int* __restrict__ cursor,
                       const int* __restrict__ partials, int N, int E) {
    int tid = threadIdx.x;
    int base = blockIdx.x * 1024 + tid * 4;
    int add = partials[blockIdx.x];
    if (base + 3 < N) {
        int4 o = *(int4*)(offs + base);
        o.x += add; o.y += add; o.z += add; o.w += add;
        *(int4*)(offs + base) = o;
        *(int4*)(cursor + base) = o;
    } else {
        for (int t = 0; t < 4; t++) {
            if (base + t < N) {
                int o = offs[base + t] + add;
                offs[base + t] = o;
                cursor[base + t] = o;
            }
        }
    }
    if (blockIdx.x == 0 && tid == 0) offs[N] = E;
}

// one 8B store per edge (col,val packed) instead of two 4B stores
__global__ void scatter_kernel(const int* __restrict__ rows, const int* __restrict__ cols,
                               const float* __restrict__ vals, int* __restrict__ cursor,
                               int2* __restrict__ ecv, int E) {
    int e = blockIdx.x * blockDim.x + threadIdx.x;
    if (e < E) {
        int r = rows[e];
        int p = atomicAdd(&cursor[r], 1);
        ecv[p] = make_int2(cols[e], __float_as_int(vals[e]));
    }
}

// ---------------- dense GEMM: C[M,64] = A[M,K] @ W[K,64], fp32 ----------------
// 64x64 output tile per 256-thread block; K-chunks of 64 staged in LDS.
// Each thread: 4 rows x 4 cols, float4 LDS reads (stride 68 pad -> <=2-way bank alias, free).
__global__ __launch_bounds__(256) void gemm_n64(const float* __restrict__ A,
                                                const float* __restrict__ W,
                                                float* __restrict__ C, int M, int K) {
    __shared__ __align__(16) float Xs[64][68];
    __shared__ __align__(16) float Ws[64][68];
    int tid = threadIdx.x;
    int row0 = blockIdx.x * 64;
    int r0 = (tid >> 4) * 4;   // 0..60
    int c0 = (tid & 15) * 4;   // 0..60
    float acc[4][4] = {};
    for (int kc = 0; kc < K; kc += 64) {
#pragma unroll
        for (int v = 0; v < 4; v++) {
            int idx = v * 256 + tid;   // 1024 float4 units per tile
            int i = idx >> 4;          // tile row (X) / tile k (W)
            int j = (idx & 15) * 4;    // tile col
            int gr = row0 + i;
            float4 g = make_float4(0.f, 0.f, 0.f, 0.f);
            if (gr < M) g = *(const float4*)(A + (size_t)gr * K + kc + j);
            *(float4*)(&Xs[i][j]) = g;
            float4 wv = *(const float4*)(W + (size_t)(kc + i) * 64 + j);
            *(float4*)(&Ws[i][j]) = wv;
        }
        __syncthreads();
#pragma unroll
        for (int j = 0; j < 64; j += 4) {
            float4 a[4], b[4];
            a[0] = *(float4*)(&Xs[r0 + 0][j]);
            a[1] = *(float4*)(&Xs[r0 + 1][j]);
            a[2] = *(float4*)(&Xs[r0 + 2][j]);
            a[3] = *(float4*)(&Xs[r0 + 3][j]);
            b[0] = *(float4*)(&Ws[j + 0][c0]);
            b[1] = *(float4*)(&Ws[j + 1][c0]);
            b[2] = *(float4*)(&Ws[j + 2][c0]);
            b[3] = *(float4*)(&Ws[j + 3][c0]);
#pragma unroll
            for (int r = 0; r < 4; r++) {
                float ar[4] = {a[r].x, a[r].y, a[r].z, a[r].w};
#pragma unroll
                for (int t = 0; t < 4; t++) {
                    float bc[4] = {b[t].x, b[t].y, b[t].z, b[t].w};
#pragma unroll
                    for (int cc = 0; cc < 4; cc++)
                        acc[r][cc] = fmaf(ar[t], bc[cc], acc[r][cc]);
                }
            }
        }
        __syncthreads();
    }
#pragma unroll
    for (int r = 0; r < 4; r++) {
        int gr = row0 + r0 + r;
        if (gr < M) {
            float4 o = make_float4(acc[r][0], acc[r][1], acc[r][2], acc[r][3]);
            *(float4*)(C + (size_t)gr * 64 + c0) = o;
        }
    }
}

// ---------------- SpMM (CSR), one wave per row, lane = feature ----------------
// Edge extent scalarized via readfirstlane -> edge loads become s_load (lgkmcnt),
// leaving vmcnt for the H gathers; 4 independent accumulation chains for MLP.
__device__ __forceinline__ float spmm_row(const int* __restrict__ offs,
                                          const int2* __restrict__ ecv,
                                          const float* __restrict__ H,
                                          int row, int lane) {
    int s = offs[row], e = offs[row + 1];
    s = __builtin_amdgcn_readfirstlane(s);
    e = __builtin_amdgcn_readfirstlane(e);
    float a0 = 0.f, a1 = 0.f, a2 = 0.f, a3 = 0.f;
    int i = s;
    for (; i + 3 < e; i += 4) {
        int2 p0 = ecv[i + 0];
        int2 p1 = ecv[i + 1];
        int2 p2 = ecv[i + 2];
        int2 p3 = ecv[i + 3];
        a0 = fmaf(__int_as_float(p0.y), H[(size_t)p0.x * 64 + lane], a0);
        a1 = fmaf(__int_as_float(p1.y), H[(size_t)p1.x * 64 + lane], a1);
        a2 = fmaf(__int_as_float(p2.y), H[(size_t)p2.x * 64 + lane], a2);
        a3 = fmaf(__int_as_float(p3.y), H[(size_t)p3.x * 64 + lane], a3);
    }
    for (; i < e; i++) {
        int2 p = ecv[i];
        a0 = fmaf(__int_as_float(p.y), H[(size_t)p.x * 64 + lane], a0);
    }
    return (a0 + a1) + (a2 + a3);
}

__global__ __launch_bounds__(256) void spmm_selu(const int* __restrict__ offs,
                                                 const int2* __restrict__ ecv,
                                                 const float* __restrict__ H,
                                                 const float* __restrict__ bias,
                                                 float* __restrict__ out, int N) {
    int row = blockIdx.x * 4 + (threadIdx.x >> 6);
    if (row >= N) return;
    int lane = threadIdx.x & 63;
    float z = spmm_row(offs, ecv, H, row, lane) + bias[lane];
    out[(size_t)row * 64 + lane] = selu_f(z);
}

__global__ __launch_bounds__(256) void spmm_norm(const int* __restrict__ offs,
                                                 const int2* __restrict__ ecv,
                                                 const float* __restrict__ H,
                                                 const float* __restrict__ bias,
                                                 float* __restrict__ out, int N) {
    int row = blockIdx.x * 4 + (threadIdx.x >> 6);
    if (row >= N) return;
    int lane = threadIdx.x & 63;
    float z = spmm_row(offs, ecv, H, row, lane) + bias[lane];
    float s2 = z * z;
#pragma unroll
    for (int d = 32; d > 0; d >>= 1) s2 += __shfl_xor(s2, d, 64);
    float inv = 1.0f / fmaxf(sqrtf(s2), 1e-12f);
    out[(size_t)row * 64 + lane] = z * inv;
}

extern "C" void kernel_launch(void* const* d_in, const int* in_sizes, int n_in,
                              void* d_out, int out_size, void* d_ws, size_t ws_size,
                              hipStream_t stream) {
    const int IN_DIM = 256, HID = 64;
    const int N = in_sizes[0] / IN_DIM;   // 100000
    const int E = in_sizes[2];            // 1200000

    const float* X[2]    = {(const float*)d_in[0], (const float*)d_in[1]};
    const int*   rows[2] = {(const int*)d_in[2], (const int*)d_in[5]};
    const int*   cols[2] = {(const int*)d_in[3], (const int*)d_in[6]};
    const float* vals[2] = {(const float*)d_in[4], (const float*)d_in[7]};
    const float* W1 = (const float*)d_in[8];
    const float* b1 = (const float*)d_in[9];
    const float* W2 = (const float*)d_in[10];
    const float* b2 = (const float*)d_in[11];
    float* out = (float*)d_out;

    // workspace carve (~62 MB)
    char* w = (char*)d_ws;
    float* bufA   = (float*)w; w += (size_t)N * HID * sizeof(float);
    float* bufB   = (float*)w; w += (size_t)N * HID * sizeof(float);
    int*   counts = (int*)w;   w += (size_t)N * sizeof(int);
    int*   offs   = (int*)w;   w += (size_t)(N + 1) * sizeof(int);
    int*   cursor = (int*)w;   w += (size_t)N * sizeof(int);
    int*   partials = (int*)w; w += 1024;
    w = (char*)(((uintptr_t)w + 15) & ~(uintptr_t)15);
    int2*  ecv    = (int2*)w;  w += (size_t)E * sizeof(int2);

    const int nbScan = (N + 1023) / 1024;          // 98 (<=128 for scan_b)
    const int nbEdge = (E + 255) / 256;            // 4688
    const int nbGemm = (N + 63) / 64;              // 1563
    const int nbRow  = (N + 3) / 4;                // 25000

    for (int g = 0; g < 2; g++) {
        // CSR build
        hipMemsetAsync(counts, 0, (size_t)N * sizeof(int), stream);
        hist_kernel<<<nbEdge, 256, 0, stream>>>(rows[g], counts, E);
        scan_a<<<nbScan, 256, 0, stream>>>(counts, offs, partials, N);
        scan_b<<<1, 128, 0, stream>>>(partials, nbScan);
        scan_c<<<nbScan, 256, 0, stream>>>(offs, cursor, partials, N, E);
        scatter_kernel<<<nbEdge, 256, 0, stream>>>(rows[g], cols[g], vals[g], cursor,
                                                   ecv, E);
        // layer 1
        gemm_n64<<<nbGemm, 256, 0, stream>>>(X[g], W1, bufA, N, IN_DIM);
        spmm_selu<<<nbRow, 256, 0, stream>>>(offs, ecv, bufA, b1, bufB, N);
        // layer 2
        gemm_n64<<<nbGemm, 256, 0, stream>>>(bufB, W2, bufA, N, HID);
        spmm_norm<<<nbRow, 256, 0, stream>>>(offs, ecv, bufA, b2,
                                             out + (size_t)g * N * HID, N);
    }
}

// Round 3
// 661.167 us; speedup vs baseline: 1.3948x; 1.2367x over previous
//
#include <hip/hip_runtime.h>
#include <hip/hip_bf16.h>

// GCN 2-layer forward, two graphs, shared weights.
// CSR build = two-level counting sort with LDS staging (all global writes
// coalesced; zero global atomics):
//   A1 bucket_hist: per-block LDS hist over NB coarse buckets (512 rows each)
//   scan over the transposed NB x nbA count matrix
//   A2 coarse_scatter: block-local LDS counting sort, coalesced run writes
//   B  fine_sort: one block per bucket, LDS sort over 512 rows, contiguous
//      output + offs[] emission
// Then per graph: H1=X@W1 -> Z=selu(spmm(H1)+b1) -> H2=Z@W2
//                 -> out=l2norm(spmm(H2)+b2).  All fp32.

#define RPB 512                 // rows per coarse bucket
#define EPB 4096                // edges per pass-A block
#define MAXB 8192               // fine-sort LDS edge capacity (26 sigma margin)

__device__ __forceinline__ float selu_f(float x) {
    const float scale = 1.0507009873554805f;
    const float alpha = 1.6732632423543772f;
    return x > 0.0f ? scale * x : scale * alpha * (__expf(x) - 1.0f);
}

// ---------------- scan (generic, used on the count matrix) ----------------
__global__ void scan_a(const int* __restrict__ counts, int* __restrict__ offs,
                       int* __restrict__ partials, int N) {
    __shared__ int sh[256];
    int tid = threadIdx.x;
    int base = blockIdx.x * 1024 + tid * 4;
    int4 c = make_int4(0, 0, 0, 0);
    if (base + 3 < N) {
        c = *(const int4*)(counts + base);
    } else {
        if (base + 0 < N) c.x = counts[base + 0];
        if (base + 1 < N) c.y = counts[base + 1];
        if (base + 2 < N) c.z = counts[base + 2];
        if (base + 3 < N) c.w = counts[base + 3];
    }
    int tsum = c.x + c.y + c.z + c.w;
    sh[tid] = tsum;
    __syncthreads();
    int val = tsum;
    for (int d = 1; d < 256; d <<= 1) {
        int t = (tid >= d) ? sh[tid - d] : 0;
        __syncthreads();
        val += t;
        sh[tid] = val;
        __syncthreads();
    }
    int excl = val - tsum;
    int4 o;
    o.x = excl; o.y = o.x + c.x; o.z = o.y + c.y; o.w = o.z + c.z;
    if (base + 3 < N) {
        *(int4*)(offs + base) = o;
    } else {
        if (base + 0 < N) offs[base + 0] = o.x;
        if (base + 1 < N) offs[base + 1] = o.y;
        if (base + 2 < N) offs[base + 2] = o.z;
        if (base + 3 < N) offs[base + 3] = o.w;
    }
    if (tid == 255) partials[blockIdx.x] = val;
}

__global__ void scan_b(int* __restrict__ partials, int nb) {
    __shared__ int sh[128];
    int tid = threadIdx.x;
    int v = (tid < nb) ? partials[tid] : 0;
    sh[tid] = v;
    __syncthreads();
    int val = v;
    for (int d = 1; d < 128; d <<= 1) {
        int t = (tid >= d) ? sh[tid - d] : 0;
        __syncthreads();
        val += t;
        sh[tid] = val;
        __syncthreads();
    }
    if (tid < nb) partials[tid] = val - v;
}

__global__ void scan_c(int* __restrict__ offs, const int* __restrict__ partials,
                       int N, int E) {
    int tid = threadIdx.x;
    int base = blockIdx.x * 1024 + tid * 4;
    int add = partials[blockIdx.x];
    if (base + 3 < N) {
        int4 o = *(int4*)(offs + base);
        o.x += add; o.y += add; o.z += add; o.w += add;
        *(int4*)(offs + base) = o;
    } else {
        for (int t = 0; t < 4; t++)
            if (base + t < N) offs[base + t] += add;
    }
    if (blockIdx.x == 0 && tid == 0) offs[N] = E;
}

// ---------------- pass A1: coarse histogram (LDS only) ----------------
__global__ __launch_bounds__(256) void bucket_hist(const int* __restrict__ rows,
                                                   int* __restrict__ cntT,
                                                   int E, int nbA, int NB) {
    __shared__ int cnt[256];
    int tid = threadIdx.x;
    cnt[tid] = 0;
    __syncthreads();
    int e0 = blockIdx.x * EPB;
#pragma unroll
    for (int k = 0; k < EPB / 256; k++) {
        int e = e0 + k * 256 + tid;
        if (e < E) atomicAdd(&cnt[rows[e] >> 9], 1);
    }
    __syncthreads();
    if (tid < NB) cntT[tid * nbA + blockIdx.x] = cnt[tid];  // transposed
}

// ---------------- pass A2: block-local counting sort, coalesced writes ------
__global__ __launch_bounds__(256) void coarse_scatter(const int* __restrict__ rows,
                                                      const int* __restrict__ cols,
                                                      const float* __restrict__ vals,
                                                      const int* __restrict__ csOffs,
                                                      int2* __restrict__ ecvA,
                                                      int E, int nbA, int NB) {
    __shared__ int cnt[256];       // hist, then cursor
    __shared__ int loc[256];       // local exclusive offsets
    __shared__ int gof[256];       // global dest base per bucket
    __shared__ int dstBase[EPB];   // per slot: gof[b] - loc[b]
    __shared__ int2 eLDS[EPB];
    int tid = threadIdx.x, blk = blockIdx.x;
    int e0 = blk * EPB;
    cnt[tid] = 0;
    __syncthreads();
#pragma unroll
    for (int k = 0; k < EPB / 256; k++) {
        int e = e0 + k * 256 + tid;
        if (e < E) atomicAdd(&cnt[rows[e] >> 9], 1);
    }
    __syncthreads();
    int my = cnt[tid];
    loc[tid] = my;
    __syncthreads();
    int val = my;  // Hillis-Steele inclusive
    for (int d = 1; d < 256; d <<= 1) {
        int t = (tid >= d) ? loc[tid - d] : 0;
        __syncthreads();
        val += t;
        loc[tid] = val;
        __syncthreads();
    }
    int excl = val - my;
    loc[tid] = excl;
    cnt[tid] = excl;  // cursor
    gof[tid] = (tid < NB) ? csOffs[tid * nbA + blk] : 0;
    __syncthreads();
#pragma unroll
    for (int k = 0; k < EPB / 256; k++) {
        int e = e0 + k * 256 + tid;
        if (e < E) {
            int r = rows[e];
            int b = r >> 9;
            int p = atomicAdd(&cnt[b], 1);
            eLDS[p] = make_int2(((r & (RPB - 1)) << 17) | cols[e],
                                __float_as_int(vals[e]));
            dstBase[p] = gof[b] - loc[b];
        }
    }
    __syncthreads();
    int nE = min(EPB, E - e0);
    for (int j = tid; j < nE; j += 256)
        ecvA[dstBase[j] + j] = eLDS[j];   // consecutive j -> consecutive dst
}

// ---------------- pass B: per-bucket fine sort in LDS ----------------
__global__ __launch_bounds__(256) void fine_sort(const int* __restrict__ csOffs,
                                                 const int2* __restrict__ ecvA,
                                                 int2* __restrict__ ecv,
                                                 int* __restrict__ offs,
                                                 int nbA, int N, int E) {
    __shared__ int rcnt[RPB], roff[RPB], rcur[RPB];
    __shared__ int sh[256];
    __shared__ int2 eLDS[MAXB];
    int b = blockIdx.x, tid = threadIdx.x;
    int bs = csOffs[b * nbA];
    int be = csOffs[(b + 1) * nbA];
    int cntE = be - bs;
    if (cntE > MAXB) cntE = MAXB;  // statistically impossible; guards LDS
    rcnt[tid] = 0;
    rcnt[tid + 256] = 0;
    __syncthreads();
    for (int j = tid; j < cntE; j += 256)
        atomicAdd(&rcnt[ecvA[bs + j].x >> 17], 1);
    __syncthreads();
    // exclusive scan of 512 with 256 threads (pairwise)
    int a0 = rcnt[2 * tid], a1 = rcnt[2 * tid + 1];
    int ps = a0 + a1;
    sh[tid] = ps;
    __syncthreads();
    int val = ps;
    for (int d = 1; d < 256; d <<= 1) {
        int t = (tid >= d) ? sh[tid - d] : 0;
        __syncthreads();
        val += t;
        sh[tid] = val;
        __syncthreads();
    }
    int exclPair = val - ps;
    roff[2 * tid] = exclPair;
    roff[2 * tid + 1] = exclPair + a0;
    rcur[2 * tid] = exclPair;
    rcur[2 * tid + 1] = exclPair + a0;
    __syncthreads();
    // emit offs for this bucket's rows
    int row0 = b * RPB;
    for (int t2 = tid; t2 < RPB; t2 += 256) {
        int row = row0 + t2;
        if (row <= N) offs[row] = bs + roff[t2];
    }
    if (b == 0 && tid == 0) offs[N] = E;  // safety (also covered by last block)
    // scatter into sorted LDS order
    for (int j = tid; j < cntE; j += 256) {
        int2 p = ecvA[bs + j];
        int pos = atomicAdd(&rcur[p.x >> 17], 1);
        if (pos < MAXB) eLDS[pos] = make_int2(p.x & 0x1FFFF, p.y);
    }
    __syncthreads();
    // contiguous coalesced writeout
    for (int j = tid; j < cntE; j += 256)
        ecv[bs + j] = eLDS[j];
}

// ---------------- dense GEMM: C[M,64] = A[M,K] @ W[K,64], fp32 ----------------
__global__ __launch_bounds__(256) void gemm_n64(const float* __restrict__ A,
                                                const float* __restrict__ W,
                                                float* __restrict__ C, int M, int K) {
    __shared__ __align__(16) float Xs[64][68];
    __shared__ __align__(16) float Ws[64][68];
    int tid = threadIdx.x;
    int row0 = blockIdx.x * 64;
    int r0 = (tid >> 4) * 4;
    int c0 = (tid & 15) * 4;
    float acc[4][4] = {};
    for (int kc = 0; kc < K; kc += 64) {
#pragma unroll
        for (int v = 0; v < 4; v++) {
            int idx = v * 256 + tid;
            int i = idx >> 4;
            int j = (idx & 15) * 4;
            int gr = row0 + i;
            float4 g = make_float4(0.f, 0.f, 0.f, 0.f);
            if (gr < M) g = *(const float4*)(A + (size_t)gr * K + kc + j);
            *(float4*)(&Xs[i][j]) = g;
            float4 wv = *(const float4*)(W + (size_t)(kc + i) * 64 + j);
            *(float4*)(&Ws[i][j]) = wv;
        }
        __syncthreads();
#pragma unroll
        for (int j = 0; j < 64; j += 4) {
            float4 a[4], bb[4];
            a[0] = *(float4*)(&Xs[r0 + 0][j]);
            a[1] = *(float4*)(&Xs[r0 + 1][j]);
            a[2] = *(float4*)(&Xs[r0 + 2][j]);
            a[3] = *(float4*)(&Xs[r0 + 3][j]);
            bb[0] = *(float4*)(&Ws[j + 0][c0]);
            bb[1] = *(float4*)(&Ws[j + 1][c0]);
            bb[2] = *(float4*)(&Ws[j + 2][c0]);
            bb[3] = *(float4*)(&Ws[j + 3][c0]);
#pragma unroll
            for (int r = 0; r < 4; r++) {
                float ar[4] = {a[r].x, a[r].y, a[r].z, a[r].w};
#pragma unroll
                for (int t = 0; t < 4; t++) {
                    float bc[4] = {bb[t].x, bb[t].y, bb[t].z, bb[t].w};
#pragma unroll
                    for (int cc = 0; cc < 4; cc++)
                        acc[r][cc] = fmaf(ar[t], bc[cc], acc[r][cc]);
                }
            }
        }
        __syncthreads();
    }
#pragma unroll
    for (int r = 0; r < 4; r++) {
        int gr = row0 + r0 + r;
        if (gr < M) {
            float4 o = make_float4(acc[r][0], acc[r][1], acc[r][2], acc[r][3]);
            *(float4*)(C + (size_t)gr * 64 + c0) = o;
        }
    }
}

// ---------------- SpMM (CSR), one wave per row, lane = feature ----------------
__device__ __forceinline__ float spmm_row(const int* __restrict__ offs,
                                          const int2* __restrict__ ecv,
                                          const float* __restrict__ H,
                                          int row, int lane) {
    int s = offs[row], e = offs[row + 1];
    s = __builtin_amdgcn_readfirstlane(s);
    e = __builtin_amdgcn_readfirstlane(e);
    float a0 = 0.f, a1 = 0.f, a2 = 0.f, a3 = 0.f;
    int i = s;
    for (; i + 3 < e; i += 4) {
        int2 p0 = ecv[i + 0];
        int2 p1 = ecv[i + 1];
        int2 p2 = ecv[i + 2];
        int2 p3 = ecv[i + 3];
        a0 = fmaf(__int_as_float(p0.y), H[(size_t)p0.x * 64 + lane], a0);
        a1 = fmaf(__int_as_float(p1.y), H[(size_t)p1.x * 64 + lane], a1);
        a2 = fmaf(__int_as_float(p2.y), H[(size_t)p2.x * 64 + lane], a2);
        a3 = fmaf(__int_as_float(p3.y), H[(size_t)p3.x * 64 + lane], a3);
    }
    for (; i < e; i++) {
        int2 p = ecv[i];
        a0 = fmaf(__int_as_float(p.y), H[(size_t)p.x * 64 + lane], a0);
    }
    return (a0 + a1) + (a2 + a3);
}

__global__ __launch_bounds__(256) void spmm_selu(const int* __restrict__ offs,
                                                 const int2* __restrict__ ecv,
                                                 const float* __restrict__ H,
                                                 const float* __restrict__ bias,
                                                 float* __restrict__ out, int N) {
    int row = blockIdx.x * 4 + (threadIdx.x >> 6);
    if (row >= N) return;
    int lane = threadIdx.x & 63;
    float z = spmm_row(offs, ecv, H, row, lane) + bias[lane];
    out[(size_t)row * 64 + lane] = selu_f(z);
}

__global__ __launch_bounds__(256) void spmm_norm(const int* __restrict__ offs,
                                                 const int2* __restrict__ ecv,
                                                 const float* __restrict__ H,
                                                 const float* __restrict__ bias,
                                                 float* __restrict__ out, int N) {
    int row = blockIdx.x * 4 + (threadIdx.x >> 6);
    if (row >= N) return;
    int lane = threadIdx.x & 63;
    float z = spmm_row(offs, ecv, H, row, lane) + bias[lane];
    float s2 = z * z;
#pragma unroll
    for (int d = 32; d > 0; d >>= 1) s2 += __shfl_xor(s2, d, 64);
    float inv = 1.0f / fmaxf(sqrtf(s2), 1e-12f);
    out[(size_t)row * 64 + lane] = z * inv;
}

extern "C" void kernel_launch(void* const* d_in, const int* in_sizes, int n_in,
                              void* d_out, int out_size, void* d_ws, size_t ws_size,
                              hipStream_t stream) {
    const int IN_DIM = 256, HID = 64;
    const int N = in_sizes[0] / IN_DIM;   // 100000
    const int E = in_sizes[2];            // 1200000

    const float* X[2]    = {(const float*)d_in[0], (const float*)d_in[1]};
    const int*   rows[2] = {(const int*)d_in[2], (const int*)d_in[5]};
    const int*   cols[2] = {(const int*)d_in[3], (const int*)d_in[6]};
    const float* vals[2] = {(const float*)d_in[4], (const float*)d_in[7]};
    const float* W1 = (const float*)d_in[8];
    const float* b1 = (const float*)d_in[9];
    const float* W2 = (const float*)d_in[10];
    const float* b2 = (const float*)d_in[11];
    float* out = (float*)d_out;

    const int NB  = (N + RPB - 1) / RPB;      // 196 coarse buckets
    const int nbA = (E + EPB - 1) / EPB;      // 293 pass-A blocks
    const int M   = NB * nbA;                 // 57428 count-matrix entries
    const int nbScanM = (M + 1023) / 1024;    // 57 (<=128 for scan_b)
    const int nbGemm = (N + 63) / 64;
    const int nbRow  = (N + 3) / 4;

    // workspace carve (~62 MB); ecvA aliases bufA (dead until gemm)
    auto align16 = [](char* p) { return (char*)(((uintptr_t)p + 15) & ~(uintptr_t)15); };
    char* w = (char*)d_ws;
    float* bufA   = (float*)w; w += (size_t)N * HID * sizeof(float);
    float* bufB   = (float*)w; w += (size_t)N * HID * sizeof(float);
    w = align16(w);
    int2*  ecv    = (int2*)w;  w += (size_t)E * sizeof(int2);
    w = align16(w);
    int*   cntT   = (int*)w;   w += (size_t)M * sizeof(int);
    w = align16(w);
    int*   csOffs = (int*)w;   w += (size_t)(M + 1) * sizeof(int);
    w = align16(w);
    int*   offs   = (int*)w;   w += (size_t)(N + 1) * sizeof(int);
    w = align16(w);
    int*   partials = (int*)w; w += 1024;
    int2*  ecvA   = (int2*)bufA;   // alias: CSR temp, dead before gemm writes bufA

    for (int g = 0; g < 2; g++) {
        // CSR build: two-level counting sort, all writes coalesced
        bucket_hist<<<nbA, 256, 0, stream>>>(rows[g], cntT, E, nbA, NB);
        scan_a<<<nbScanM, 256, 0, stream>>>(cntT, csOffs, partials, M);
        scan_b<<<1, 128, 0, stream>>>(partials, nbScanM);
        scan_c<<<nbScanM, 256, 0, stream>>>(csOffs, partials, M, E);
        coarse_scatter<<<nbA, 256, 0, stream>>>(rows[g], cols[g], vals[g], csOffs,
                                                ecvA, E, nbA, NB);
        fine_sort<<<NB, 256, 0, stream>>>(csOffs, ecvA, ecv, offs, nbA, N, E);
        // layer 1
        gemm_n64<<<nbGemm, 256, 0, stream>>>(X[g], W1, bufA, N, IN_DIM);
        spmm_selu<<<nbRow, 256, 0, stream>>>(offs, ecv, bufA, b1, bufB, N);
        // layer 2
        gemm_n64<<<nbGemm, 256, 0, stream>>>(bufB, W2, bufA, N, HID);
        spmm_norm<<<nbRow, 256, 0, stream>>>(offs, ecv, bufA, b2,
                                             out + (size_t)g * N * HID, N);
    }
}

// Round 4
// 616.672 us; speedup vs baseline: 1.4954x; 1.0722x over previous
//
#include <hip/hip_runtime.h>
#include <hip/hip_bf16.h>

// GCN 2-layer forward, two graphs, shared weights.
// CSR build: two-level counting sort (unchanged from R3).
// GEMM: MFMA 16x16x32 bf16, split-bf16 3-term (Xh@Wh + Xl@Wh + Xh@Wl) ->
//       fp32-equivalent accuracy at MFMA rate. W pre-transposed/converted once.
// SpMM: one wave/row, 4 edges per gather instruction (16 lanes x float4 each),
//       butterfly combine; selu / l2norm fused epilogues.

#define RPB 512
#define EPB 4096
#define MAXB 8192

typedef __attribute__((ext_vector_type(8))) short short8;
typedef __attribute__((ext_vector_type(4))) short short4v;
typedef __attribute__((ext_vector_type(4))) float f32x4;

__device__ __forceinline__ float selu_f(float x) {
    const float scale = 1.0507009873554805f;
    const float alpha = 1.6732632423543772f;
    return x > 0.0f ? scale * x : scale * alpha * (__expf(x) - 1.0f);
}

__device__ __forceinline__ short f2bf(float x) {   // RNE truncate fp32->bf16
    unsigned u = __float_as_uint(x);
    u += 0x7FFF + ((u >> 16) & 1);
    return (short)(u >> 16);
}
__device__ __forceinline__ float bf2f(short h) {
    return __uint_as_float(((unsigned)(unsigned short)h) << 16);
}

// ---------------- scan (generic) ----------------
__global__ void scan_a(const int* __restrict__ counts, int* __restrict__ offs,
                       int* __restrict__ partials, int N) {
    __shared__ int sh[256];
    int tid = threadIdx.x;
    int base = blockIdx.x * 1024 + tid * 4;
    int4 c = make_int4(0, 0, 0, 0);
    if (base + 3 < N) {
        c = *(const int4*)(counts + base);
    } else {
        if (base + 0 < N) c.x = counts[base + 0];
        if (base + 1 < N) c.y = counts[base + 1];
        if (base + 2 < N) c.z = counts[base + 2];
        if (base + 3 < N) c.w = counts[base + 3];
    }
    int tsum = c.x + c.y + c.z + c.w;
    sh[tid] = tsum;
    __syncthreads();
    int val = tsum;
    for (int d = 1; d < 256; d <<= 1) {
        int t = (tid >= d) ? sh[tid - d] : 0;
        __syncthreads();
        val += t;
        sh[tid] = val;
        __syncthreads();
    }
    int excl = val - tsum;
    int4 o;
    o.x = excl; o.y = o.x + c.x; o.z = o.y + c.y; o.w = o.z + c.z;
    if (base + 3 < N) {
        *(int4*)(offs + base) = o;
    } else {
        if (base + 0 < N) offs[base + 0] = o.x;
        if (base + 1 < N) offs[base + 1] = o.y;
        if (base + 2 < N) offs[base + 2] = o.z;
        if (base + 3 < N) offs[base + 3] = o.w;
    }
    if (tid == 255) partials[blockIdx.x] = val;
}

__global__ void scan_b(int* __restrict__ partials, int nb) {
    __shared__ int sh[128];
    int tid = threadIdx.x;
    int v = (tid < nb) ? partials[tid] : 0;
    sh[tid] = v;
    __syncthreads();
    int val = v;
    for (int d = 1; d < 128; d <<= 1) {
        int t = (tid >= d) ? sh[tid - d] : 0;
        __syncthreads();
        val += t;
        sh[tid] = val;
        __syncthreads();
    }
    if (tid < nb) partials[tid] = val - v;
}

__global__ void scan_c(int* __restrict__ offs, const int* __restrict__ partials,
                       int N, int E) {
    int tid = threadIdx.x;
    int base = blockIdx.x * 1024 + tid * 4;
    int add = partials[blockIdx.x];
    if (base + 3 < N) {
        int4 o = *(int4*)(offs + base);
        o.x += add; o.y += add; o.z += add; o.w += add;
        *(int4*)(offs + base) = o;
    } else {
        for (int t = 0; t < 4; t++)
            if (base + t < N) offs[base + t] += add;
    }
    if (blockIdx.x == 0 && tid == 0) offs[N] = E;
}

// ---------------- pass A1: coarse histogram ----------------
__global__ __launch_bounds__(256) void bucket_hist(const int* __restrict__ rows,
                                                   int* __restrict__ cntT,
                                                   int E, int nbA, int NB) {
    __shared__ int cnt[256];
    int tid = threadIdx.x;
    cnt[tid] = 0;
    __syncthreads();
    int e0 = blockIdx.x * EPB;
#pragma unroll
    for (int k = 0; k < EPB / 256; k++) {
        int e = e0 + k * 256 + tid;
        if (e < E) atomicAdd(&cnt[rows[e] >> 9], 1);
    }
    __syncthreads();
    if (tid < NB) cntT[tid * nbA + blockIdx.x] = cnt[tid];
}

// ---------------- pass A2: block-local counting sort ----------------
__global__ __launch_bounds__(256) void coarse_scatter(const int* __restrict__ rows,
                                                      const int* __restrict__ cols,
                                                      const float* __restrict__ vals,
                                                      const int* __restrict__ csOffs,
                                                      int2* __restrict__ ecvA,
                                                      int E, int nbA, int NB) {
    __shared__ int cnt[256];
    __shared__ int loc[256];
    __shared__ int gof[256];
    __shared__ int dstBase[EPB];
    __shared__ int2 eLDS[EPB];
    int tid = threadIdx.x, blk = blockIdx.x;
    int e0 = blk * EPB;
    cnt[tid] = 0;
    __syncthreads();
#pragma unroll
    for (int k = 0; k < EPB / 256; k++) {
        int e = e0 + k * 256 + tid;
        if (e < E) atomicAdd(&cnt[rows[e] >> 9], 1);
    }
    __syncthreads();
    int my = cnt[tid];
    loc[tid] = my;
    __syncthreads();
    int val = my;
    for (int d = 1; d < 256; d <<= 1) {
        int t = (tid >= d) ? loc[tid - d] : 0;
        __syncthreads();
        val += t;
        loc[tid] = val;
        __syncthreads();
    }
    int excl = val - my;
    loc[tid] = excl;
    cnt[tid] = excl;
    gof[tid] = (tid < NB) ? csOffs[tid * nbA + blk] : 0;
    __syncthreads();
#pragma unroll
    for (int k = 0; k < EPB / 256; k++) {
        int e = e0 + k * 256 + tid;
        if (e < E) {
            int r = rows[e];
            int b = r >> 9;
            int p = atomicAdd(&cnt[b], 1);
            eLDS[p] = make_int2(((r & (RPB - 1)) << 17) | cols[e],
                                __float_as_int(vals[e]));
            dstBase[p] = gof[b] - loc[b];
        }
    }
    __syncthreads();
    int nE = min(EPB, E - e0);
    for (int j = tid; j < nE; j += 256)
        ecvA[dstBase[j] + j] = eLDS[j];
}

// ---------------- pass B: per-bucket fine sort ----------------
__global__ __launch_bounds__(256) void fine_sort(const int* __restrict__ csOffs,
                                                 const int2* __restrict__ ecvA,
                                                 int2* __restrict__ ecv,
                                                 int* __restrict__ offs,
                                                 int nbA, int N, int E) {
    __shared__ int rcnt[RPB], roff[RPB], rcur[RPB];
    __shared__ int sh[256];
    __shared__ int2 eLDS[MAXB];
    int b = blockIdx.x, tid = threadIdx.x;
    int bs = csOffs[b * nbA];
    int be = csOffs[(b + 1) * nbA];
    int cntE = be - bs;
    if (cntE > MAXB) cntE = MAXB;
    rcnt[tid] = 0;
    rcnt[tid + 256] = 0;
    __syncthreads();
    for (int j = tid; j < cntE; j += 256)
        atomicAdd(&rcnt[ecvA[bs + j].x >> 17], 1);
    __syncthreads();
    int a0 = rcnt[2 * tid], a1 = rcnt[2 * tid + 1];
    int ps = a0 + a1;
    sh[tid] = ps;
    __syncthreads();
    int val = ps;
    for (int d = 1; d < 256; d <<= 1) {
        int t = (tid >= d) ? sh[tid - d] : 0;
        __syncthreads();
        val += t;
        sh[tid] = val;
        __syncthreads();
    }
    int exclPair = val - ps;
    roff[2 * tid] = exclPair;
    roff[2 * tid + 1] = exclPair + a0;
    rcur[2 * tid] = exclPair;
    rcur[2 * tid + 1] = exclPair + a0;
    __syncthreads();
    int row0 = b * RPB;
    for (int t2 = tid; t2 < RPB; t2 += 256) {
        int row = row0 + t2;
        if (row <= N) offs[row] = bs + roff[t2];
    }
    if (b == 0 && tid == 0) offs[N] = E;
    for (int j = tid; j < cntE; j += 256) {
        int2 p = ecvA[bs + j];
        int pos = atomicAdd(&rcur[p.x >> 17], 1);
        if (pos < MAXB) eLDS[pos] = make_int2(p.x & 0x1FFFF, p.y);
    }
    __syncthreads();
    for (int j = tid; j < cntE; j += 256)
        ecv[bs + j] = eLDS[j];
}

// ---------------- weight prep: fp32 [K][64] -> bf16 hi/lo transposed [64][K] --
__global__ void prep_w(const float* __restrict__ W, short* __restrict__ th,
                       short* __restrict__ tl, int K) {
    int idx = blockIdx.x * 256 + threadIdx.x;
    if (idx < K * 64) {
        int k = idx >> 6, n = idx & 63;
        float x = W[idx];
        short h = f2bf(x);
        short l = f2bf(x - bf2f(h));
        th[n * K + k] = h;
        tl[n * K + k] = l;
    }
}

// ---------------- MFMA GEMM: C[M,64] = A[M,K] @ W[K,64] ----------------
// Split-bf16: A = Ah + Al (in-kernel cvt), W pre-split. 3 MFMA terms.
// Block: 256 thr = 4 waves; tile 64 rows x 64 cols; wave w -> rows 16w..16w+15,
// 4 N-tiles of 16. K-chunks of 64 (2 k-instances of 32 per MFMA tile).
__global__ __launch_bounds__(256) void gemm_mfma(const float* __restrict__ A,
                                                 const short* __restrict__ Wth,
                                                 const short* __restrict__ Wtl,
                                                 float* __restrict__ C, int M, int K) {
    __shared__ short Ah[64 * 72], Al[64 * 72];   // [row][k], stride 72 (pad 8)
    __shared__ short Wh[64 * 72], Wl[64 * 72];   // [n][k],   stride 72
    int tid = threadIdx.x;
    int wave = tid >> 6, lane = tid & 63;
    int m = lane & 15, q = lane >> 4;
    int row0 = blockIdx.x * 64;
    f32x4 acc[4] = {{0.f, 0.f, 0.f, 0.f}, {0.f, 0.f, 0.f, 0.f},
                    {0.f, 0.f, 0.f, 0.f}, {0.f, 0.f, 0.f, 0.f}};
    for (int kc = 0; kc < K; kc += 64) {
        // stage A tile (64x64 fp32 -> bf16 hi/lo)
#pragma unroll
        for (int v = 0; v < 4; v++) {
            int idx = v * 256 + tid;
            int i = idx >> 4;
            int j4 = (idx & 15) * 4;
            int gr = row0 + i;
            float4 g = make_float4(0.f, 0.f, 0.f, 0.f);
            if (gr < M) g = *(const float4*)(A + (size_t)gr * K + kc + j4);
            short4v h, l;
            h.x = f2bf(g.x); l.x = f2bf(g.x - bf2f(h.x));
            h.y = f2bf(g.y); l.y = f2bf(g.y - bf2f(h.y));
            h.z = f2bf(g.z); l.z = f2bf(g.z - bf2f(h.z));
            h.w = f2bf(g.w); l.w = f2bf(g.w - bf2f(h.w));
            *(short4v*)(&Ah[i * 72 + j4]) = h;
            *(short4v*)(&Al[i * 72 + j4]) = l;
        }
        // stage W tile (pre-split bf16, [n][K] layout)
#pragma unroll
        for (int v = 0; v < 4; v++) {
            int idx = v * 256 + tid;
            int n = idx >> 4;
            int k4 = (idx & 15) * 4;
            short4v hv = *(const short4v*)(Wth + (size_t)n * K + kc + k4);
            short4v lv = *(const short4v*)(Wtl + (size_t)n * K + kc + k4);
            *(short4v*)(&Wh[n * 72 + k4]) = hv;
            *(short4v*)(&Wl[n * 72 + k4]) = lv;
        }
        __syncthreads();
        int ar = (16 * wave + m) * 72;
        short8 ah0 = *(const short8*)(&Ah[ar + q * 8]);
        short8 ah1 = *(const short8*)(&Ah[ar + 32 + q * 8]);
        short8 al0 = *(const short8*)(&Al[ar + q * 8]);
        short8 al1 = *(const short8*)(&Al[ar + 32 + q * 8]);
#pragma unroll
        for (int nt = 0; nt < 4; nt++) {
            int nb = (nt * 16 + m) * 72;
            short8 bh0 = *(const short8*)(&Wh[nb + q * 8]);
            short8 bh1 = *(const short8*)(&Wh[nb + 32 + q * 8]);
            short8 bl0 = *(const short8*)(&Wl[nb + q * 8]);
            short8 bl1 = *(const short8*)(&Wl[nb + 32 + q * 8]);
            acc[nt] = __builtin_amdgcn_mfma_f32_16x16x32_bf16(ah0, bh0, acc[nt], 0, 0, 0);
            acc[nt] = __builtin_amdgcn_mfma_f32_16x16x32_bf16(al0, bh0, acc[nt], 0, 0, 0);
            acc[nt] = __builtin_amdgcn_mfma_f32_16x16x32_bf16(ah0, bl0, acc[nt], 0, 0, 0);
            acc[nt] = __builtin_amdgcn_mfma_f32_16x16x32_bf16(ah1, bh1, acc[nt], 0, 0, 0);
            acc[nt] = __builtin_amdgcn_mfma_f32_16x16x32_bf16(al1, bh1, acc[nt], 0, 0, 0);
            acc[nt] = __builtin_amdgcn_mfma_f32_16x16x32_bf16(ah1, bl1, acc[nt], 0, 0, 0);
        }
        __syncthreads();
    }
    // epilogue: C/D layout col=lane&15, row=q*4+reg
#pragma unroll
    for (int nt = 0; nt < 4; nt++) {
#pragma unroll
        for (int r = 0; r < 4; r++) {
            int grow = row0 + 16 * wave + q * 4 + r;
            if (grow < M) C[(size_t)grow * 64 + nt * 16 + m] = acc[nt][r];
        }
    }
}

// ---------------- SpMM: one wave/row, 4 edges per gather instruction ---------
// lane = 16*g + t: group g in [0,4) handles edge i+g, thread t covers features
// 4t..4t+3 as float4. Butterfly (xor 16,32) combines groups at row end.
__device__ __forceinline__ void spmm_row4(const int* __restrict__ offs,
                                          const int2* __restrict__ ecv,
                                          const float* __restrict__ H,
                                          int row, int g, int f4,
                                          float& ax, float& ay, float& az, float& aw) {
    int s = offs[row], e = offs[row + 1];
    s = __builtin_amdgcn_readfirstlane(s);
    e = __builtin_amdgcn_readfirstlane(e);
    ax = ay = az = aw = 0.f;
    for (int i = s; i < e; i += 8) {
        int i0 = i + g, i1 = i + 4 + g;
        int2 p0 = ecv[i0 < e ? i0 : (e - 1)];
        int2 p1 = ecv[i1 < e ? i1 : (e - 1)];
        float v0 = (i0 < e) ? __int_as_float(p0.y) : 0.f;
        float v1 = (i1 < e) ? __int_as_float(p1.y) : 0.f;
        float4 h0 = *(const float4*)(H + (size_t)p0.x * 64 + f4);
        float4 h1 = *(const float4*)(H + (size_t)p1.x * 64 + f4);
        ax = fmaf(v0, h0.x, ax); ay = fmaf(v0, h0.y, ay);
        az = fmaf(v0, h0.z, az); aw = fmaf(v0, h0.w, aw);
        ax = fmaf(v1, h1.x, ax); ay = fmaf(v1, h1.y, ay);
        az = fmaf(v1, h1.z, az); aw = fmaf(v1, h1.w, aw);
    }
#pragma unroll
    for (int d = 16; d <= 32; d <<= 1) {
        ax += __shfl_xor(ax, d, 64);
        ay += __shfl_xor(ay, d, 64);
        az += __shfl_xor(az, d, 64);
        aw += __shfl_xor(aw, d, 64);
    }
}

__global__ __launch_bounds__(256) void spmm_selu(const int* __restrict__ offs,
                                                 const int2* __restrict__ ecv,
                                                 const float* __restrict__ H,
                                                 const float* __restrict__ bias,
                                                 float* __restrict__ out, int N) {
    int row = blockIdx.x * 4 + (threadIdx.x >> 6);
    if (row >= N) return;
    int lane = threadIdx.x & 63;
    int g = lane >> 4, f4 = (lane & 15) * 4;
    float ax, ay, az, aw;
    spmm_row4(offs, ecv, H, row, g, f4, ax, ay, az, aw);
    float4 b = *(const float4*)(bias + f4);
    if (g == 0) {
        float4 o;
        o.x = selu_f(ax + b.x);
        o.y = selu_f(ay + b.y);
        o.z = selu_f(az + b.z);
        o.w = selu_f(aw + b.w);
        *(float4*)(out + (size_t)row * 64 + f4) = o;
    }
}

__global__ __launch_bounds__(256) void spmm_norm(const int* __restrict__ offs,
                                                 const int2* __restrict__ ecv,
                                                 const float* __restrict__ H,
                                                 const float* __restrict__ bias,
                                                 float* __restrict__ out, int N) {
    int row = blockIdx.x * 4 + (threadIdx.x >> 6);
    if (row >= N) return;
    int lane = threadIdx.x & 63;
    int g = lane >> 4, f4 = (lane & 15) * 4;
    float ax, ay, az, aw;
    spmm_row4(offs, ecv, H, row, g, f4, ax, ay, az, aw);
    float4 b = *(const float4*)(bias + f4);
    float zx = ax + b.x, zy = ay + b.y, zz = az + b.z, zw = aw + b.w;
    float s2 = zx * zx + zy * zy + zz * zz + zw * zw;
#pragma unroll
    for (int d = 1; d <= 8; d <<= 1) s2 += __shfl_xor(s2, d, 64);
    float inv = 1.0f / fmaxf(sqrtf(s2), 1e-12f);
    if (g == 0) {
        float4 o;
        o.x = zx * inv; o.y = zy * inv; o.z = zz * inv; o.w = zw * inv;
        *(float4*)(out + (size_t)row * 64 + f4) = o;
    }
}

extern "C" void kernel_launch(void* const* d_in, const int* in_sizes, int n_in,
                              void* d_out, int out_size, void* d_ws, size_t ws_size,
                              hipStream_t stream) {
    const int IN_DIM = 256, HID = 64;
    const int N = in_sizes[0] / IN_DIM;   // 100000
    const int E = in_sizes[2];            // 1200000

    const float* X[2]    = {(const float*)d_in[0], (const float*)d_in[1]};
    const int*   rows[2] = {(const int*)d_in[2], (const int*)d_in[5]};
    const int*   cols[2] = {(const int*)d_in[3], (const int*)d_in[6]};
    const float* vals[2] = {(const float*)d_in[4], (const float*)d_in[7]};
    const float* W1 = (const float*)d_in[8];
    const float* b1 = (const float*)d_in[9];
    const float* W2 = (const float*)d_in[10];
    const float* b2 = (const float*)d_in[11];
    float* out = (float*)d_out;

    const int NB  = (N + RPB - 1) / RPB;      // 196
    const int nbA = (E + EPB - 1) / EPB;      // 293
    const int M   = NB * nbA;
    const int nbScanM = (M + 1023) / 1024;    // 57
    const int nbGemm = (N + 63) / 64;         // 1563
    const int nbRow  = (N + 3) / 4;           // 25000

    auto align16 = [](char* p) { return (char*)(((uintptr_t)p + 15) & ~(uintptr_t)15); };
    char* w = (char*)d_ws;
    float* bufA   = (float*)w; w += (size_t)N * HID * sizeof(float);
    float* bufB   = (float*)w; w += (size_t)N * HID * sizeof(float);
    w = align16(w);
    int2*  ecv    = (int2*)w;  w += (size_t)E * sizeof(int2);
    w = align16(w);
    int*   cntT   = (int*)w;   w += (size_t)M * sizeof(int);
    w = align16(w);
    int*   csOffs = (int*)w;   w += (size_t)(M + 1) * sizeof(int);
    w = align16(w);
    int*   offs   = (int*)w;   w += (size_t)(N + 1) * sizeof(int);
    w = align16(w);
    int*   partials = (int*)w; w += 1024;
    w = align16(w);
    short* w1th = (short*)w;   w += (size_t)64 * IN_DIM * sizeof(short);
    short* w1tl = (short*)w;   w += (size_t)64 * IN_DIM * sizeof(short);
    short* w2th = (short*)w;   w += (size_t)64 * HID * sizeof(short);
    short* w2tl = (short*)w;   w += (size_t)64 * HID * sizeof(short);
    int2*  ecvA = (int2*)bufA;   // alias: CSR temp, dead before gemm writes bufA

    // weight prep (tiny, once per call)
    prep_w<<<(IN_DIM * 64 + 255) / 256, 256, 0, stream>>>(W1, w1th, w1tl, IN_DIM);
    prep_w<<<(HID * 64 + 255) / 256, 256, 0, stream>>>(W2, w2th, w2tl, HID);

    for (int g = 0; g < 2; g++) {
        // CSR build
        bucket_hist<<<nbA, 256, 0, stream>>>(rows[g], cntT, E, nbA, NB);
        scan_a<<<nbScanM, 256, 0, stream>>>(cntT, csOffs, partials, M);
        scan_b<<<1, 128, 0, stream>>>(partials, nbScanM);
        scan_c<<<nbScanM, 256, 0, stream>>>(csOffs, partials, M, E);
        coarse_scatter<<<nbA, 256, 0, stream>>>(rows[g], cols[g], vals[g], csOffs,
                                                ecvA, E, nbA, NB);
        fine_sort<<<NB, 256, 0, stream>>>(csOffs, ecvA, ecv, offs, nbA, N, E);
        // layer 1
        gemm_mfma<<<nbGemm, 256, 0, stream>>>(X[g], w1th, w1tl, bufA, N, IN_DIM);
        spmm_selu<<<nbRow, 256, 0, stream>>>(offs, ecv, bufA, b1, bufB, N);
        // layer 2
        gemm_mfma<<<nbGemm, 256, 0, stream>>>(bufB, w2th, w2tl, bufA, N, HID);
        spmm_norm<<<nbRow, 256, 0, stream>>>(offs, ecv, bufA, b2,
                                             out + (size_t)g * N * HID, N);
    }
}